// Round 3
// baseline (259.108 us; speedup 1.0000x reference)
//
#include <hip/hip_runtime.h>
#include <math.h>

#define VV 50257
#define VPAD 50304   // 393 * 128
#define DD 128
#define BB 1024
#define CC 10

typedef short bf16x8 __attribute__((ext_vector_type(8)));
typedef float f32x4 __attribute__((ext_vector_type(4)));

__device__ inline float bf2f(unsigned short u) {
    return __uint_as_float(((unsigned)u) << 16);
}
__device__ inline unsigned short f2bf(float f) {
    unsigned u = __float_as_uint(f);
    unsigned r = ((u >> 16) & 1) + 0x7FFF;
    return (unsigned short)((u + r) >> 16);
}

// Fragment-packed operand layout: chunk = (group*NKI + kI)*64 + quad*16 + l15,
// each chunk = 8 bf16 (16B); row group*16+l15, k = kI*32+quad*8+e.

// ---------------------------------------------------------------------------
// Kernel 0 (16 blocks): pack W_enc -> WeP; block 0 zeroes the k_lse ticket
// counter (stream-ordered two launches ahead of its use).
// ---------------------------------------------------------------------------
__global__ __launch_bounds__(256) void k_prep0(
    const float* __restrict__ W_enc, unsigned short* __restrict__ WeP,
    unsigned int* __restrict__ counter)
{
    __shared__ float tl[256][17];
    const int jg = blockIdx.x, tid = threadIdx.x;
    if (jg == 0 && tid == 0) counter[0] = 0u;
#pragma unroll
    for (int i = 0; i < 16; ++i) {
        int idx = i * 256 + tid;
        int k = idx >> 4, j = idx & 15;
        tl[k][j] = W_enc[(size_t)k * 256 + jg * 16 + j];
    }
    __syncthreads();
#pragma unroll
    for (int i = 0; i < 2; ++i) {
        int c = i * 256 + tid;
        int l15 = c & 15, q = (c >> 4) & 3, kI = c >> 6;
        bf16x8 o;
#pragma unroll
        for (int e = 0; e < 8; ++e)
            o[e] = (short)f2bf(tl[kI * 32 + q * 8 + e][l15]);
        *(bf16x8*)(WeP + (((size_t)jg * 8 + kI) * 64 + q * 16 + l15) * 8) = o;
    }
}

// ---------------------------------------------------------------------------
// Kernel 1 (822 blocks):
//   bid 0..31   = fused encoder: h[b][j] = sum_c relu([ce;cx_c] @ W_enc + b).
//                 ce @ W_top is c-invariant -> computed ONCE (acc_ce), then
//                 per c only the cx @ W_bot half (4 kI) is MFMA'd. 16 b-tiles
//                 x 2 n-halves; h written f32 (replaces bf16 enc_relu).
//   bid 32..817 = W_vocab -> WvP fragment pack (HBM stream, overlaps enc).
//   bid 818..821= W_mean/W_var -> Wmv interleave (used only next launch).
// ---------------------------------------------------------------------------
#define AS_STRIDE 520
__global__ __launch_bounds__(256) void k_main(
    const int* __restrict__ center_id, const int* __restrict__ context_ids,
    const float* __restrict__ emb, const unsigned short* __restrict__ WeP,
    const float* __restrict__ b_enc, const float* __restrict__ Wv,
    const float* __restrict__ W_mean, const float* __restrict__ W_var,
    unsigned short* __restrict__ WvP, unsigned short* __restrict__ Wmv,
    float* __restrict__ h)
{
    __shared__ __align__(16) unsigned char smraw[50688];
    const int bid = blockIdx.x, tid = threadIdx.x;

    if (bid >= 818) {
        // ---- Wmv interleave pack ----
        const int b4 = bid - 818;
#pragma unroll
        for (int i = 0; i < 32; ++i) {
            int idx = b4 * 8192 + i * 256 + tid;
            unsigned short m = f2bf(W_mean[idx]);
            unsigned short v = f2bf(W_var[idx]);
            *(ushort2*)(Wmv + (size_t)idx * 2) = make_ushort2(m, v);
        }
        return;
    }

    if (bid >= 32) {
        // ---- W_vocab pack path ----
        float (*tile)[65] = (float (*)[65])smraw;
        const int s = bid - 32;           // 0..785
        const int v0 = s * 64;
#pragma unroll
        for (int i = 0; i < 32; ++i) {
            int idx = tid + i * 256;
            int k = idx >> 6, j = idx & 63;
            int v = v0 + j;
            tile[k][j] = (v < VV) ? Wv[(size_t)k * VV + v] : 0.f;
        }
        __syncthreads();
#pragma unroll
        for (int i = 0; i < 4; ++i) {
            int c = i * 256 + tid;
            int l15 = c & 15, q = (c >> 4) & 3, kI = (c >> 6) & 3, g = c >> 8;
            bf16x8 o;
#pragma unroll
            for (int e = 0; e < 8; ++e)
                o[e] = (short)f2bf(tile[kI * 32 + q * 8 + e][g * 16 + l15]);
            size_t vg = (size_t)s * 4 + g;
            *(bf16x8*)(WvP + ((vg * 4 + kI) * 64 + q * 16 + l15) * 8) = o;
        }
        return;
    }

    // ---- fused encoder path ----
    unsigned short* As = (unsigned short*)smraw;                 // 32*520*2 B

    const int lane = tid & 63;
    const int wid  = tid >> 6;
    const int wm   = wid & 1;
    const int wn   = wid >> 1;
    const int quad = lane >> 4;
    const int l15  = lane & 15;

    const int bt = bid & 15;
    const int zt = bid >> 4;
    const int b0 = bt * 64;
    const int n0 = zt * 128;

    const int rlane = tid >> 4;       // 0..15
    const int c8    = tid & 15;       // k-chunk (8 k's)
    const int kIc   = c8 >> 2, qc = c8 & 3;

    // stage ce half (kI slots 0..3) once
#pragma unroll
    for (int p = 0; p < 4; ++p) {
        int r = p * 16 + rlane;
        int rid_ce = center_id[b0 + r];
        const float* s0 = emb + (size_t)rid_ce * 128 + c8 * 8;
        float4 a0 = *(const float4*)s0, a1 = *(const float4*)(s0 + 4);
        bf16x8 oa;
        oa[0] = (short)f2bf(a0.x); oa[1] = (short)f2bf(a0.y);
        oa[2] = (short)f2bf(a0.z); oa[3] = (short)f2bf(a0.w);
        oa[4] = (short)f2bf(a1.x); oa[5] = (short)f2bf(a1.y);
        oa[6] = (short)f2bf(a1.z); oa[7] = (short)f2bf(a1.w);
        *(bf16x8*)(As + (size_t)(p * 8 + kIc) * AS_STRIDE + (qc * 16 + rlane) * 8) = oa;
    }
    // stage cx for c=0 (kI slots 4..7)
#pragma unroll
    for (int p = 0; p < 4; ++p) {
        int r = p * 16 + rlane;
        int rid_cx = context_ids[(b0 + r) * CC + 0];
        const float* s1 = emb + (size_t)rid_cx * 128 + c8 * 8;
        float4 b0v = *(const float4*)s1, b1v = *(const float4*)(s1 + 4);
        bf16x8 ob;
        ob[0] = (short)f2bf(b0v.x); ob[1] = (short)f2bf(b0v.y);
        ob[2] = (short)f2bf(b0v.z); ob[3] = (short)f2bf(b0v.w);
        ob[4] = (short)f2bf(b1v.x); ob[5] = (short)f2bf(b1v.y);
        ob[6] = (short)f2bf(b1v.z); ob[7] = (short)f2bf(b1v.w);
        *(bf16x8*)(As + (size_t)(p * 8 + kIc + 4) * AS_STRIDE + (qc * 16 + rlane) * 8) = ob;
    }
    __syncthreads();

    float benc[4];
#pragma unroll
    for (int nt = 0; nt < 4; ++nt)
        benc[nt] = b_enc[n0 + wn * 64 + nt * 16 + l15];

    // hoist bottom-half B fragments (kI 4..7) into registers
    bf16x8 bbot[4][4];
#pragma unroll
    for (int nt = 0; nt < 4; ++nt) {
        size_t jg = (size_t)zt * 8 + wn * 4 + nt;
#pragma unroll
        for (int kI = 0; kI < 4; ++kI)
            bbot[nt][kI] = *(const bf16x8*)(WeP + ((jg * 8 + kI + 4) * 64 + lane) * 8);
    }

    // acc_ce = ce @ W_top (c-invariant, kI 0..3)
    f32x4 acc_ce[2][4];
#pragma unroll
    for (int mt = 0; mt < 2; ++mt)
#pragma unroll
        for (int nt = 0; nt < 4; ++nt) acc_ce[mt][nt] = (f32x4){0.f, 0.f, 0.f, 0.f};
#pragma unroll
    for (int kI = 0; kI < 4; ++kI) {
        bf16x8 a[2], b[4];
#pragma unroll
        for (int mt = 0; mt < 2; ++mt)
            a[mt] = *(const bf16x8*)(As + (size_t)((wm * 2 + mt) * 8 + kI) * AS_STRIDE + lane * 8);
#pragma unroll
        for (int nt = 0; nt < 4; ++nt) {
            size_t jg = (size_t)zt * 8 + wn * 4 + nt;
            b[nt] = *(const bf16x8*)(WeP + ((jg * 8 + kI) * 64 + lane) * 8);
        }
#pragma unroll
        for (int mt = 0; mt < 2; ++mt)
#pragma unroll
            for (int nt = 0; nt < 4; ++nt)
                acc_ce[mt][nt] = __builtin_amdgcn_mfma_f32_16x16x32_bf16(
                    a[mt], b[nt], acc_ce[mt][nt], 0, 0, 0);
    }

    float hacc[2][4][4];
#pragma unroll
    for (int mt = 0; mt < 2; ++mt)
#pragma unroll
        for (int nt = 0; nt < 4; ++nt)
#pragma unroll
            for (int reg = 0; reg < 4; ++reg) hacc[mt][nt][reg] = 0.f;

    for (int c = 0; c < CC; ++c) {
        f32x4 acc[2][4];
#pragma unroll
        for (int mt = 0; mt < 2; ++mt)
#pragma unroll
            for (int nt = 0; nt < 4; ++nt) acc[mt][nt] = acc_ce[mt][nt];
#pragma unroll
        for (int kI = 0; kI < 4; ++kI) {
            bf16x8 a[2];
#pragma unroll
            for (int mt = 0; mt < 2; ++mt)
                a[mt] = *(const bf16x8*)(As + (size_t)((wm * 2 + mt) * 8 + kI + 4) * AS_STRIDE + lane * 8);
#pragma unroll
            for (int mt = 0; mt < 2; ++mt)
#pragma unroll
                for (int nt = 0; nt < 4; ++nt)
                    acc[mt][nt] = __builtin_amdgcn_mfma_f32_16x16x32_bf16(
                        a[mt], bbot[nt][kI], acc[mt][nt], 0, 0, 0);
        }
#pragma unroll
        for (int mt = 0; mt < 2; ++mt)
#pragma unroll
            for (int nt = 0; nt < 4; ++nt)
#pragma unroll
                for (int reg = 0; reg < 4; ++reg)
                    hacc[mt][nt][reg] += fmaxf(acc[mt][nt][reg] + benc[nt], 0.f);

        if (c < CC - 1) {
            __syncthreads();    // all waves done reading cx_c
#pragma unroll
            for (int p = 0; p < 4; ++p) {
                int r = p * 16 + rlane;
                int rid_cx = context_ids[(b0 + r) * CC + (c + 1)];
                const float* s1 = emb + (size_t)rid_cx * 128 + c8 * 8;
                float4 b0v = *(const float4*)s1, b1v = *(const float4*)(s1 + 4);
                bf16x8 ob;
                ob[0] = (short)f2bf(b0v.x); ob[1] = (short)f2bf(b0v.y);
                ob[2] = (short)f2bf(b0v.z); ob[3] = (short)f2bf(b0v.w);
                ob[4] = (short)f2bf(b1v.x); ob[5] = (short)f2bf(b1v.y);
                ob[6] = (short)f2bf(b1v.z); ob[7] = (short)f2bf(b1v.w);
                *(bf16x8*)(As + (size_t)(p * 8 + kIc + 4) * AS_STRIDE + (qc * 16 + rlane) * 8) = ob;
            }
            __syncthreads();    // staging visible
        }
    }

    // transpose h through LDS for coalesced f32 writes
    __syncthreads();            // As dead; reuse smraw
    float (*Csf)[132] = (float (*)[132])smraw;
#pragma unroll
    for (int mt = 0; mt < 2; ++mt)
#pragma unroll
        for (int nt = 0; nt < 4; ++nt) {
            int col = wn * 64 + nt * 16 + l15;
#pragma unroll
            for (int reg = 0; reg < 4; ++reg) {
                int row = wm * 32 + mt * 16 + quad * 4 + reg;
                Csf[row][col] = hacc[mt][nt][reg];
            }
        }
    __syncthreads();
#pragma unroll
    for (int it = 0; it < 8; ++it) {
        int ch = it * 256 + tid;
        int row = ch >> 5, cg = ch & 31;
        *(float4*)&h[(size_t)(b0 + row) * 256 + n0 + cg * 4] = *(const float4*)&Csf[row][cg * 4];
    }
}

// ---------------------------------------------------------------------------
// Kernel 2: latent heads + KL + context logits. 256 blocks x 512 threads,
// four batch rows per block, split-K 4 over the Wmv GEMV. Phase 1 is now a
// plain f32 load of fused h (c-sum moved into k_main).
// ---------------------------------------------------------------------------
__global__ __launch_bounds__(512) void k_latent(
    const float* __restrict__ h, const unsigned short* __restrict__ Wmv,
    const float* __restrict__ b_mean, const float* __restrict__ b_var,
    const float* __restrict__ epsilon,
    const int* __restrict__ center_id, const int* __restrict__ context_ids,
    const unsigned short* __restrict__ WvP, const float* __restrict__ bv,
    const float* __restrict__ prior_means, const float* __restrict__ prior_vars,
    unsigned short* __restrict__ z_pack, float* __restrict__ kl,
    float* __restrict__ ctxsum, float* __restrict__ out)
{
    __shared__ __align__(16) float hs[4][256];
    __shared__ float mpart[3][4][128], vpart[3][4][128];
    __shared__ float zsh[4][128];
    __shared__ float red[4][2];
    __shared__ float credw[4][2];
    const int tid = threadIdx.x;
    const int b0 = blockIdx.x * 4;

    if (blockIdx.x == 0 && tid == 0) out[0] = 0.f;

    // ---- phase 1: load h ----
    {
        const int col = tid & 255;
        const int rr  = tid >> 8;         // 0,1
#pragma unroll
        for (int r2 = 0; r2 < 2; ++r2) {
            int row = rr * 2 + r2;
            hs[row][col] = h[(size_t)(b0 + row) * 256 + col];
        }
    }
    __syncthreads();

    // ---- phase 2: split-K GEMV for mean/var heads ----
    const int d    = tid & 127;
    const int part = tid >> 7;            // 0..3
    const int kbase = part * 64;
    float m[4], vr[4];
#pragma unroll
    for (int r = 0; r < 4; ++r) {
        m[r]  = part ? 0.f : b_mean[d];
        vr[r] = part ? 0.f : b_var[d];
    }
    for (int k0 = 0; k0 < 64; k0 += 4) {
        float4 h4[4];
#pragma unroll
        for (int r = 0; r < 4; ++r)
            h4[r] = *(const float4*)&hs[r][kbase + k0];
#pragma unroll
        for (int kk = 0; kk < 4; ++kk) {
            ushort2 u = *(const ushort2*)(Wmv + ((size_t)(kbase + k0 + kk) * 128 + d) * 2);
            float wm_ = bf2f(u.x), wv_ = bf2f(u.y);
#pragma unroll
            for (int r = 0; r < 4; ++r) {
                float hk = ((const float*)&h4[r])[kk];
                m[r]  += hk * wm_;
                vr[r] += hk * wv_;
            }
        }
    }
    if (part) {
#pragma unroll
        for (int r = 0; r < 4; ++r) {
            mpart[part - 1][r][d] = m[r];
            vpart[part - 1][r][d] = vr[r];
        }
    }
    __syncthreads();

    // ---- phase 3: combine, var/z/KL (threads 0..127 only) ----
    if (tid < 128) {
        const int wid = tid >> 6;         // 0,1
        const int kIz = d >> 5, qz = (d >> 3) & 3, ez = d & 7;
        const int bg = b0 >> 4;
#pragma unroll
        for (int r = 0; r < 4; ++r) {
            float mm = m[r]  + mpart[0][r][d] + mpart[1][r][d] + mpart[2][r][d];
            float vv = vr[r] + vpart[0][r][d] + vpart[1][r][d] + vpart[2][r][d];

            float var = (vv > 20.f) ? vv : log1pf(__expf(vv));
            float zd = mm + __expf(0.5f * var) * epsilon[d];
            unsigned short zu = f2bf(zd);
            const int bb = b0 + r;
            const int l15b = bb & 15;
            z_pack[(((size_t)(bg * 4 + kIz)) * 64 + qz * 16 + l15b) * 8 + ez] = zu;
            zsh[r][d] = bf2f(zu);

            int cid = center_id[bb];
            float pm  = prior_means[(size_t)cid * 128 + d];
            float pvr = prior_vars[(size_t)cid * 128 + d];
            float pv  = (pvr > 20.f) ? pvr : log1pf(__expf(pvr));
            float diff = pm - mm;
            float t = var / pv + diff * diff / pv - 1.f + logf(pv) - logf(var);
#pragma unroll
            for (int off = 32; off; off >>= 1) t += __shfl_xor(t, off, 64);
            if ((tid & 63) == 0) red[r][wid] = t;
        }
    }
    __syncthreads();

    // ---- phase 4: context logits, wave w = (p-half, row) ----
    {
        const int w     = tid >> 6;       // 0..7
        const int row   = w & 3;
        const int phalf = w >> 2;         // 0: p 0..4, 1: p 5..9
        const int lane  = tid & 63;
        const float z1 = zsh[row][lane];
        const float z2 = zsh[row][lane + 64];
        const int kI1 = lane >> 5, q1 = (lane >> 3) & 3, e1 = lane & 7;
        const int d2  = lane + 64;
        const int kI2 = d2 >> 5,  q2 = (d2 >> 3) & 3,  e2 = d2 & 7;
        float cacc = 0.f;
#pragma unroll
        for (int pp = 0; pp < 5; ++pp) {
            int p = phalf * 5 + pp;
            int cid = context_ids[(b0 + row) * CC + p];
            int vg = cid >> 4, l15v = cid & 15;
            float w1 = bf2f(WvP[(((size_t)(vg * 4 + kI1)) * 64 + q1 * 16 + l15v) * 8 + e1]);
            float w2 = bf2f(WvP[(((size_t)(vg * 4 + kI2)) * 64 + q2 * 16 + l15v) * 8 + e2]);
            float cs = z1 * w1 + z2 * w2;
#pragma unroll
            for (int off = 32; off; off >>= 1) cs += __shfl_xor(cs, off, 64);
            cacc += cs + bv[cid];
        }
        if (lane == 0) credw[row][phalf] = cacc;
    }
    __syncthreads();
    if (tid < 4) {
        kl[b0 + tid]     = 0.5f * (red[tid][0] + red[tid][1]);
        ctxsum[b0 + tid] = credw[tid][0] + credw[tid][1];
    }
}

// ---------------------------------------------------------------------------
// Kernel 3: streaming MFMA GEMM + exp-sum + fused final reduce.
// Grid (8,50,2): x = bx+8*by (XCD-pinned slice), mg = bz picks mi_g 0..3 or
// 4..7 -> each block does 4 m-steps, so WvP B-frags load 2x total (was 4x).
// Tail: decoupled-lookback style -- threadfence + device atomic ticket; the
// last 64 blocks to finish spin until all 800 arrive, then do k_reduce's job
// (rocprim-style release/acquire via __threadfence, device-scope atomics).
// ---------------------------------------------------------------------------
#define LSE_BLOCKS 800
#define RED_BLOCKS 64
__global__ __launch_bounds__(256) void k_lse(
    const unsigned short* __restrict__ z_pack, const unsigned short* __restrict__ WvP,
    const float* __restrict__ bv, float* __restrict__ partial,
    const float* __restrict__ ctxsum, const float* __restrict__ kl,
    unsigned int* __restrict__ counter, float* __restrict__ out)
{
    __shared__ float pl[2][128][20];
    __shared__ float bred[4];
    __shared__ unsigned int ticket;
    const int x = blockIdx.x + 8 * blockIdx.y;   // vocab slice 0..399
    const int mg = blockIdx.z;                   // 0..1
    const int tid  = threadIdx.x;

    if (x < 393) {
        const int lane = tid & 63;
        const int wid  = tid >> 6;
        const int wm   = wid & 1;
        const int wn   = wid >> 1;
        const int quad = lane >> 4;
        const int l15  = lane & 15;
        const int n0   = x * 128;

        bf16x8 bfr[4][4];
#pragma unroll
        for (int nt = 0; nt < 4; ++nt) {
            size_t vg = (size_t)x * 8 + wn * 4 + nt;
#pragma unroll
            for (int kI = 0; kI < 4; ++kI)
                bfr[nt][kI] = *(const bf16x8*)(WvP + ((vg * 4 + kI) * 64 + lane) * 8);
        }

        float bvf[4];
#pragma unroll
        for (int nt = 0; nt < 4; ++nt) {
            int n = n0 + wn * 64 + nt * 16 + l15;
            bvf[nt] = (n < VV) ? bv[n] : -__builtin_huge_valf();
        }

#pragma unroll
        for (int mi = 0; mi < 4; ++mi) {
            const int mi_g = mg * 4 + mi;        // 0..7

            f32x4 acc[4][4];
#pragma unroll
            for (int mt = 0; mt < 4; ++mt)
#pragma unroll
                for (int nt = 0; nt < 4; ++nt) acc[mt][nt] = (f32x4){0.f, 0.f, 0.f, 0.f};

#pragma unroll
            for (int kI = 0; kI < 4; ++kI) {
                bf16x8 afr[4];
#pragma unroll
                for (int mt = 0; mt < 4; ++mt) {
                    size_t bg = (size_t)mi_g * 8 + wm * 4 + mt;
                    afr[mt] = *(const bf16x8*)(z_pack + ((bg * 4 + kI) * 64 + lane) * 8);
                }
#pragma unroll
                for (int mt = 0; mt < 4; ++mt)
#pragma unroll
                    for (int nt = 0; nt < 4; ++nt)
                        acc[mt][nt] = __builtin_amdgcn_mfma_f32_16x16x32_bf16(
                            afr[mt], bfr[nt][kI], acc[mt][nt], 0, 0, 0);
            }

#pragma unroll
            for (int mt = 0; mt < 4; ++mt)
#pragma unroll
                for (int reg = 0; reg < 4; ++reg) {
                    float s = 0.f;
#pragma unroll
                    for (int nt = 0; nt < 4; ++nt)
                        s += __expf(acc[mt][nt][reg] + bvf[nt]);
                    pl[wn][wm * 64 + mt * 16 + quad * 4 + reg][l15] = s;
                }
            __syncthreads();
            if (tid < 128) {
                const float* p0 = &pl[0][tid][0];
                const float* p1 = &pl[1][tid][0];
                float4 a0 = *(const float4*)(p0);
                float4 a1 = *(const float4*)(p0 + 4);
                float4 a2 = *(const float4*)(p0 + 8);
                float4 a3 = *(const float4*)(p0 + 12);
                float4 b0 = *(const float4*)(p1);
                float4 b1 = *(const float4*)(p1 + 4);
                float4 b2 = *(const float4*)(p1 + 8);
                float4 b3 = *(const float4*)(p1 + 12);
                float tot = (a0.x + a0.y + a0.z + a0.w) + (a1.x + a1.y + a1.z + a1.w)
                          + (a2.x + a2.y + a2.z + a2.w) + (a3.x + a3.y + a3.z + a3.w)
                          + (b0.x + b0.y + b0.z + b0.w) + (b1.x + b1.y + b1.z + b1.w)
                          + (b2.x + b2.y + b2.z + b2.w) + (b3.x + b3.y + b3.z + b3.w);
                partial[(size_t)x * 1024 + mi_g * 128 + tid] = tot;
            }
            __syncthreads();
        }
    }

    // ---- tail handshake: last 64 arrivals do the final reduce ----
    __threadfence();
    if (tid == 0) ticket = atomicAdd(counter, 1u);
    __syncthreads();
    const unsigned int old = ticket;
    if (old >= (unsigned)(LSE_BLOCKS - RED_BLOCKS)) {
        const int slice = (int)old - (LSE_BLOCKS - RED_BLOCKS);
        if (slice < RED_BLOCKS) {   // guard (rocprof single-kernel replay)
            if (tid == 0) {
                while (atomicAdd(counter, 0u) < (unsigned)LSE_BLOCKS)
                    __builtin_amdgcn_s_sleep(2);
            }
            __syncthreads();
            __threadfence();

            const int row = slice * 16 + (tid >> 4);
            const int part = tid & 15;
            float s = 0.f;
            for (int vb = part; vb < 393; vb += 16)
                s += partial[(size_t)vb * 1024 + row];
            s += __shfl_xor(s, 1, 64);
            s += __shfl_xor(s, 2, 64);
            s += __shfl_xor(s, 4, 64);
            s += __shfl_xor(s, 8, 64);

            float v = 0.f;
            if (part == 0)
                v = ctxsum[row] - 10.f * logf(s) - kl[row];
            v += __shfl_xor(v, 16, 64);
            v += __shfl_xor(v, 32, 64);
            if ((tid & 63) == 0) bred[tid >> 6] = v;
            __syncthreads();
            if (tid == 0)
                atomicAdd(out, (bred[0] + bred[1] + bred[2] + bred[3]) * (1.f / 1024.f));
        }
    }
}

// ---------------------------------------------------------------------------
extern "C" void kernel_launch(void* const* d_in, const int* in_sizes, int n_in,
                              void* d_out, int out_size, void* d_ws, size_t ws_size,
                              hipStream_t stream)
{
    const int*   center_id   = (const int*)d_in[0];
    const int*   context_ids = (const int*)d_in[1];
    const float* epsilon     = (const float*)d_in[2];
    const float* emb         = (const float*)d_in[3];
    const float* prior_means = (const float*)d_in[4];
    const float* prior_vars  = (const float*)d_in[5];
    const float* W_enc       = (const float*)d_in[6];
    const float* b_enc       = (const float*)d_in[7];
    const float* W_mean      = (const float*)d_in[8];
    const float* b_mean      = (const float*)d_in[9];
    const float* W_var       = (const float*)d_in[10];
    const float* b_var       = (const float*)d_in[11];
    const float* W_vocab     = (const float*)d_in[12];
    const float* b_vocab     = (const float*)d_in[13];

    float* out = (float*)d_out;
    char*  ws  = (char*)d_ws;

    size_t off = 0;
    unsigned short* WvP      = (unsigned short*)(ws + off); off += 12877824;  // 50304*128*2
    unsigned short* WeP      = (unsigned short*)(ws + off); off += 131072;    // 256*256*2
    unsigned short* Wmv      = (unsigned short*)(ws + off); off += 131072;    // 256*128*2*2
    unsigned short* z_pack   = (unsigned short*)(ws + off); off += 262144;    // 1024*128*2
    float*          h        = (float*)(ws + off);          off += 1048576;   // 1024*256*4
    float*          kl       = (float*)(ws + off);          off += 4096;
    float*          ctxsum   = (float*)(ws + off);          off += 4096;
    float*          partial  = (float*)(ws + off);          off += 1609728;   // 393*1024*4
    unsigned int*   counter  = (unsigned int*)(ws + off);   off += 4096;

    k_prep0<<<16, 256, 0, stream>>>(W_enc, WeP, counter);
    k_main<<<822, 256, 0, stream>>>(center_id, context_ids, emb, WeP, b_enc,
                                    W_vocab, W_mean, W_var, WvP, Wmv, h);
    k_latent<<<256, 512, 0, stream>>>(h, Wmv, b_mean, b_var, epsilon,
                                      center_id, context_ids, WvP, b_vocab,
                                      prior_means, prior_vars, z_pack, kl,
                                      ctxsum, out);
    k_lse<<<dim3(8, 50, 2), 256, 0, stream>>>(z_pack, WvP, b_vocab, partial,
                                              ctxsum, kl, counter, out);
}

// Round 4
// 203.103 us; speedup vs baseline: 1.2757x; 1.2757x over previous
//
#include <hip/hip_runtime.h>
#include <math.h>

#define VV 50257
#define VPAD 50304   // 393 * 128
#define DD 128
#define BB 1024
#define CC 10

typedef short bf16x8 __attribute__((ext_vector_type(8)));
typedef float f32x4 __attribute__((ext_vector_type(4)));

__device__ inline float bf2f(unsigned short u) {
    return __uint_as_float(((unsigned)u) << 16);
}
__device__ inline unsigned short f2bf(float f) {
    unsigned u = __float_as_uint(f);
    unsigned r = ((u >> 16) & 1) + 0x7FFF;
    return (unsigned short)((u + r) >> 16);
}

// Fragment-packed operand layout: chunk = (group*NKI + kI)*64 + quad*16 + l15,
// each chunk = 8 bf16 (16B); row group*16+l15, k = kI*32+quad*8+e.

// ---------------------------------------------------------------------------
// Kernel 0 (16 blocks): pack W_enc -> WeP.
// ---------------------------------------------------------------------------
__global__ __launch_bounds__(256) void k_prep0(
    const float* __restrict__ W_enc, unsigned short* __restrict__ WeP)
{
    __shared__ float tl[256][17];
    const int jg = blockIdx.x, tid = threadIdx.x;
#pragma unroll
    for (int i = 0; i < 16; ++i) {
        int idx = i * 256 + tid;
        int k = idx >> 4, j = idx & 15;
        tl[k][j] = W_enc[(size_t)k * 256 + jg * 16 + j];
    }
    __syncthreads();
#pragma unroll
    for (int i = 0; i < 2; ++i) {
        int c = i * 256 + tid;
        int l15 = c & 15, q = (c >> 4) & 3, kI = c >> 6;
        bf16x8 o;
#pragma unroll
        for (int e = 0; e < 8; ++e)
            o[e] = (short)f2bf(tl[kI * 32 + q * 8 + e][l15]);
        *(bf16x8*)(WeP + (((size_t)jg * 8 + kI) * 64 + q * 16 + l15) * 8) = o;
    }
}

// ---------------------------------------------------------------------------
// Kernel 1 (822 blocks):
//   bid 0..31   = fused encoder: h[b][j] = sum_c relu([ce;cx_c] @ W_enc + b).
//                 ce @ W_top is c-invariant -> computed ONCE (acc_ce), then
//                 per c only the cx @ W_bot half (4 kI) is MFMA'd. 16 b-tiles
//                 x 2 n-halves; h written f32.
//   bid 32..817 = W_vocab -> WvP fragment pack (HBM stream, overlaps enc).
//   bid 818..821= W_mean/W_var -> Wmv interleave (used only next launch).
// ---------------------------------------------------------------------------
#define AS_STRIDE 520
__global__ __launch_bounds__(256) void k_main(
    const int* __restrict__ center_id, const int* __restrict__ context_ids,
    const float* __restrict__ emb, const unsigned short* __restrict__ WeP,
    const float* __restrict__ b_enc, const float* __restrict__ Wv,
    const float* __restrict__ W_mean, const float* __restrict__ W_var,
    unsigned short* __restrict__ WvP, unsigned short* __restrict__ Wmv,
    float* __restrict__ h)
{
    __shared__ __align__(16) unsigned char smraw[50688];
    const int bid = blockIdx.x, tid = threadIdx.x;

    if (bid >= 818) {
        // ---- Wmv interleave pack ----
        const int b4 = bid - 818;
#pragma unroll
        for (int i = 0; i < 32; ++i) {
            int idx = b4 * 8192 + i * 256 + tid;
            unsigned short m = f2bf(W_mean[idx]);
            unsigned short v = f2bf(W_var[idx]);
            *(ushort2*)(Wmv + (size_t)idx * 2) = make_ushort2(m, v);
        }
        return;
    }

    if (bid >= 32) {
        // ---- W_vocab pack path ----
        float (*tile)[65] = (float (*)[65])smraw;
        const int s = bid - 32;           // 0..785
        const int v0 = s * 64;
#pragma unroll
        for (int i = 0; i < 32; ++i) {
            int idx = tid + i * 256;
            int k = idx >> 6, j = idx & 63;
            int v = v0 + j;
            tile[k][j] = (v < VV) ? Wv[(size_t)k * VV + v] : 0.f;
        }
        __syncthreads();
#pragma unroll
        for (int i = 0; i < 4; ++i) {
            int c = i * 256 + tid;
            int l15 = c & 15, q = (c >> 4) & 3, kI = (c >> 6) & 3, g = c >> 8;
            bf16x8 o;
#pragma unroll
            for (int e = 0; e < 8; ++e)
                o[e] = (short)f2bf(tile[kI * 32 + q * 8 + e][g * 16 + l15]);
            size_t vg = (size_t)s * 4 + g;
            *(bf16x8*)(WvP + ((vg * 4 + kI) * 64 + q * 16 + l15) * 8) = o;
        }
        return;
    }

    // ---- fused encoder path ----
    unsigned short* As = (unsigned short*)smraw;                 // 32*520*2 B

    const int lane = tid & 63;
    const int wid  = tid >> 6;
    const int wm   = wid & 1;
    const int wn   = wid >> 1;
    const int quad = lane >> 4;
    const int l15  = lane & 15;

    const int bt = bid & 15;
    const int zt = bid >> 4;
    const int b0 = bt * 64;
    const int n0 = zt * 128;

    const int rlane = tid >> 4;       // 0..15
    const int c8    = tid & 15;       // k-chunk (8 k's)
    const int kIc   = c8 >> 2, qc = c8 & 3;

    // stage ce half (kI slots 0..3) once
#pragma unroll
    for (int p = 0; p < 4; ++p) {
        int r = p * 16 + rlane;
        int rid_ce = center_id[b0 + r];
        const float* s0 = emb + (size_t)rid_ce * 128 + c8 * 8;
        float4 a0 = *(const float4*)s0, a1 = *(const float4*)(s0 + 4);
        bf16x8 oa;
        oa[0] = (short)f2bf(a0.x); oa[1] = (short)f2bf(a0.y);
        oa[2] = (short)f2bf(a0.z); oa[3] = (short)f2bf(a0.w);
        oa[4] = (short)f2bf(a1.x); oa[5] = (short)f2bf(a1.y);
        oa[6] = (short)f2bf(a1.z); oa[7] = (short)f2bf(a1.w);
        *(bf16x8*)(As + (size_t)(p * 8 + kIc) * AS_STRIDE + (qc * 16 + rlane) * 8) = oa;
    }
    // stage cx for c=0 (kI slots 4..7)
#pragma unroll
    for (int p = 0; p < 4; ++p) {
        int r = p * 16 + rlane;
        int rid_cx = context_ids[(b0 + r) * CC + 0];
        const float* s1 = emb + (size_t)rid_cx * 128 + c8 * 8;
        float4 b0v = *(const float4*)s1, b1v = *(const float4*)(s1 + 4);
        bf16x8 ob;
        ob[0] = (short)f2bf(b0v.x); ob[1] = (short)f2bf(b0v.y);
        ob[2] = (short)f2bf(b0v.z); ob[3] = (short)f2bf(b0v.w);
        ob[4] = (short)f2bf(b1v.x); ob[5] = (short)f2bf(b1v.y);
        ob[6] = (short)f2bf(b1v.z); ob[7] = (short)f2bf(b1v.w);
        *(bf16x8*)(As + (size_t)(p * 8 + kIc + 4) * AS_STRIDE + (qc * 16 + rlane) * 8) = ob;
    }
    __syncthreads();

    float benc[4];
#pragma unroll
    for (int nt = 0; nt < 4; ++nt)
        benc[nt] = b_enc[n0 + wn * 64 + nt * 16 + l15];

    // hoist bottom-half B fragments (kI 4..7) into registers
    bf16x8 bbot[4][4];
#pragma unroll
    for (int nt = 0; nt < 4; ++nt) {
        size_t jg = (size_t)zt * 8 + wn * 4 + nt;
#pragma unroll
        for (int kI = 0; kI < 4; ++kI)
            bbot[nt][kI] = *(const bf16x8*)(WeP + ((jg * 8 + kI + 4) * 64 + lane) * 8);
    }

    // acc_ce = ce @ W_top (c-invariant, kI 0..3)
    f32x4 acc_ce[2][4];
#pragma unroll
    for (int mt = 0; mt < 2; ++mt)
#pragma unroll
        for (int nt = 0; nt < 4; ++nt) acc_ce[mt][nt] = (f32x4){0.f, 0.f, 0.f, 0.f};
#pragma unroll
    for (int kI = 0; kI < 4; ++kI) {
        bf16x8 a[2], b[4];
#pragma unroll
        for (int mt = 0; mt < 2; ++mt)
            a[mt] = *(const bf16x8*)(As + (size_t)((wm * 2 + mt) * 8 + kI) * AS_STRIDE + lane * 8);
#pragma unroll
        for (int nt = 0; nt < 4; ++nt) {
            size_t jg = (size_t)zt * 8 + wn * 4 + nt;
            b[nt] = *(const bf16x8*)(WeP + ((jg * 8 + kI) * 64 + lane) * 8);
        }
#pragma unroll
        for (int mt = 0; mt < 2; ++mt)
#pragma unroll
            for (int nt = 0; nt < 4; ++nt)
                acc_ce[mt][nt] = __builtin_amdgcn_mfma_f32_16x16x32_bf16(
                    a[mt], b[nt], acc_ce[mt][nt], 0, 0, 0);
    }

    float hacc[2][4][4];
#pragma unroll
    for (int mt = 0; mt < 2; ++mt)
#pragma unroll
        for (int nt = 0; nt < 4; ++nt)
#pragma unroll
            for (int reg = 0; reg < 4; ++reg) hacc[mt][nt][reg] = 0.f;

    for (int c = 0; c < CC; ++c) {
        f32x4 acc[2][4];
#pragma unroll
        for (int mt = 0; mt < 2; ++mt)
#pragma unroll
            for (int nt = 0; nt < 4; ++nt) acc[mt][nt] = acc_ce[mt][nt];
#pragma unroll
        for (int kI = 0; kI < 4; ++kI) {
            bf16x8 a[2];
#pragma unroll
            for (int mt = 0; mt < 2; ++mt)
                a[mt] = *(const bf16x8*)(As + (size_t)((wm * 2 + mt) * 8 + kI + 4) * AS_STRIDE + lane * 8);
#pragma unroll
            for (int mt = 0; mt < 2; ++mt)
#pragma unroll
                for (int nt = 0; nt < 4; ++nt)
                    acc[mt][nt] = __builtin_amdgcn_mfma_f32_16x16x32_bf16(
                        a[mt], bbot[nt][kI], acc[mt][nt], 0, 0, 0);
        }
#pragma unroll
        for (int mt = 0; mt < 2; ++mt)
#pragma unroll
            for (int nt = 0; nt < 4; ++nt)
#pragma unroll
                for (int reg = 0; reg < 4; ++reg)
                    hacc[mt][nt][reg] += fmaxf(acc[mt][nt][reg] + benc[nt], 0.f);

        if (c < CC - 1) {
            __syncthreads();    // all waves done reading cx_c
#pragma unroll
            for (int p = 0; p < 4; ++p) {
                int r = p * 16 + rlane;
                int rid_cx = context_ids[(b0 + r) * CC + (c + 1)];
                const float* s1 = emb + (size_t)rid_cx * 128 + c8 * 8;
                float4 b0v = *(const float4*)s1, b1v = *(const float4*)(s1 + 4);
                bf16x8 ob;
                ob[0] = (short)f2bf(b0v.x); ob[1] = (short)f2bf(b0v.y);
                ob[2] = (short)f2bf(b0v.z); ob[3] = (short)f2bf(b0v.w);
                ob[4] = (short)f2bf(b1v.x); ob[5] = (short)f2bf(b1v.y);
                ob[6] = (short)f2bf(b1v.z); ob[7] = (short)f2bf(b1v.w);
                *(bf16x8*)(As + (size_t)(p * 8 + kIc + 4) * AS_STRIDE + (qc * 16 + rlane) * 8) = ob;
            }
            __syncthreads();    // staging visible
        }
    }

    // transpose h through LDS for coalesced f32 writes
    __syncthreads();            // As dead; reuse smraw
    float (*Csf)[132] = (float (*)[132])smraw;
#pragma unroll
    for (int mt = 0; mt < 2; ++mt)
#pragma unroll
        for (int nt = 0; nt < 4; ++nt) {
            int col = wn * 64 + nt * 16 + l15;
#pragma unroll
            for (int reg = 0; reg < 4; ++reg) {
                int row = wm * 32 + mt * 16 + quad * 4 + reg;
                Csf[row][col] = hacc[mt][nt][reg];
            }
        }
    __syncthreads();
#pragma unroll
    for (int it = 0; it < 8; ++it) {
        int ch = it * 256 + tid;
        int row = ch >> 5, cg = ch & 31;
        *(float4*)&h[(size_t)(b0 + row) * 256 + n0 + cg * 4] = *(const float4*)&Csf[row][cg * 4];
    }
}

// ---------------------------------------------------------------------------
// Kernel 2: latent heads + KL + context logits. 256 blocks x 512 threads,
// four batch rows per block, split-K 4 over the Wmv GEMV.
// ---------------------------------------------------------------------------
__global__ __launch_bounds__(512) void k_latent(
    const float* __restrict__ h, const unsigned short* __restrict__ Wmv,
    const float* __restrict__ b_mean, const float* __restrict__ b_var,
    const float* __restrict__ epsilon,
    const int* __restrict__ center_id, const int* __restrict__ context_ids,
    const unsigned short* __restrict__ WvP, const float* __restrict__ bv,
    const float* __restrict__ prior_means, const float* __restrict__ prior_vars,
    unsigned short* __restrict__ z_pack, float* __restrict__ kl,
    float* __restrict__ ctxsum, float* __restrict__ out)
{
    __shared__ __align__(16) float hs[4][256];
    __shared__ float mpart[3][4][128], vpart[3][4][128];
    __shared__ float zsh[4][128];
    __shared__ float red[4][2];
    __shared__ float credw[4][2];
    const int tid = threadIdx.x;
    const int b0 = blockIdx.x * 4;

    if (blockIdx.x == 0 && tid == 0) out[0] = 0.f;

    // ---- phase 1: load h ----
    {
        const int col = tid & 255;
        const int rr  = tid >> 8;         // 0,1
#pragma unroll
        for (int r2 = 0; r2 < 2; ++r2) {
            int row = rr * 2 + r2;
            hs[row][col] = h[(size_t)(b0 + row) * 256 + col];
        }
    }
    __syncthreads();

    // ---- phase 2: split-K GEMV for mean/var heads ----
    const int d    = tid & 127;
    const int part = tid >> 7;            // 0..3
    const int kbase = part * 64;
    float m[4], vr[4];
#pragma unroll
    for (int r = 0; r < 4; ++r) {
        m[r]  = part ? 0.f : b_mean[d];
        vr[r] = part ? 0.f : b_var[d];
    }
    for (int k0 = 0; k0 < 64; k0 += 4) {
        float4 h4[4];
#pragma unroll
        for (int r = 0; r < 4; ++r)
            h4[r] = *(const float4*)&hs[r][kbase + k0];
#pragma unroll
        for (int kk = 0; kk < 4; ++kk) {
            ushort2 u = *(const ushort2*)(Wmv + ((size_t)(kbase + k0 + kk) * 128 + d) * 2);
            float wm_ = bf2f(u.x), wv_ = bf2f(u.y);
#pragma unroll
            for (int r = 0; r < 4; ++r) {
                float hk = ((const float*)&h4[r])[kk];
                m[r]  += hk * wm_;
                vr[r] += hk * wv_;
            }
        }
    }
    if (part) {
#pragma unroll
        for (int r = 0; r < 4; ++r) {
            mpart[part - 1][r][d] = m[r];
            vpart[part - 1][r][d] = vr[r];
        }
    }
    __syncthreads();

    // ---- phase 3: combine, var/z/KL (threads 0..127 only) ----
    if (tid < 128) {
        const int wid = tid >> 6;         // 0,1
        const int kIz = d >> 5, qz = (d >> 3) & 3, ez = d & 7;
        const int bg = b0 >> 4;
#pragma unroll
        for (int r = 0; r < 4; ++r) {
            float mm = m[r]  + mpart[0][r][d] + mpart[1][r][d] + mpart[2][r][d];
            float vv = vr[r] + vpart[0][r][d] + vpart[1][r][d] + vpart[2][r][d];

            float var = (vv > 20.f) ? vv : log1pf(__expf(vv));
            float zd = mm + __expf(0.5f * var) * epsilon[d];
            unsigned short zu = f2bf(zd);
            const int bb = b0 + r;
            const int l15b = bb & 15;
            z_pack[(((size_t)(bg * 4 + kIz)) * 64 + qz * 16 + l15b) * 8 + ez] = zu;
            zsh[r][d] = bf2f(zu);

            int cid = center_id[bb];
            float pm  = prior_means[(size_t)cid * 128 + d];
            float pvr = prior_vars[(size_t)cid * 128 + d];
            float pv  = (pvr > 20.f) ? pvr : log1pf(__expf(pvr));
            float diff = pm - mm;
            float t = var / pv + diff * diff / pv - 1.f + logf(pv) - logf(var);
#pragma unroll
            for (int off = 32; off; off >>= 1) t += __shfl_xor(t, off, 64);
            if ((tid & 63) == 0) red[r][wid] = t;
        }
    }
    __syncthreads();

    // ---- phase 4: context logits, wave w = (p-half, row) ----
    {
        const int w     = tid >> 6;       // 0..7
        const int row   = w & 3;
        const int phalf = w >> 2;         // 0: p 0..4, 1: p 5..9
        const int lane  = tid & 63;
        const float z1 = zsh[row][lane];
        const float z2 = zsh[row][lane + 64];
        const int kI1 = lane >> 5, q1 = (lane >> 3) & 3, e1 = lane & 7;
        const int d2  = lane + 64;
        const int kI2 = d2 >> 5,  q2 = (d2 >> 3) & 3,  e2 = d2 & 7;
        float cacc = 0.f;
#pragma unroll
        for (int pp = 0; pp < 5; ++pp) {
            int p = phalf * 5 + pp;
            int cid = context_ids[(b0 + row) * CC + p];
            int vg = cid >> 4, l15v = cid & 15;
            float w1 = bf2f(WvP[(((size_t)(vg * 4 + kI1)) * 64 + q1 * 16 + l15v) * 8 + e1]);
            float w2 = bf2f(WvP[(((size_t)(vg * 4 + kI2)) * 64 + q2 * 16 + l15v) * 8 + e2]);
            float cs = z1 * w1 + z2 * w2;
#pragma unroll
            for (int off = 32; off; off >>= 1) cs += __shfl_xor(cs, off, 64);
            cacc += cs + bv[cid];
        }
        if (lane == 0) credw[row][phalf] = cacc;
    }
    __syncthreads();
    if (tid < 4) {
        kl[b0 + tid]     = 0.5f * (red[tid][0] + red[tid][1]);
        ctxsum[b0 + tid] = credw[tid][0] + credw[tid][1];
    }
}

// ---------------------------------------------------------------------------
// Kernel 3: streaming MFMA GEMM + exp-sum. Grid (8,50,2): x = bx+8*by
// (XCD-pinned slice), mg = bz picks mi_g 0..3 or 4..7 -> each block does 4
// m-steps, WvP B-frags loaded 2x total. Private per-block partial rows; the
// final reduce stays a SEPARATE launch (R3 lesson: in-kernel threadfence +
// atomic-ticket tail cost ~80 us of idle spin -- never again).
// ---------------------------------------------------------------------------
__global__ __launch_bounds__(256) void k_lse(
    const unsigned short* __restrict__ z_pack, const unsigned short* __restrict__ WvP,
    const float* __restrict__ bv, float* __restrict__ partial)
{
    __shared__ float pl[2][128][20];
    const int x = blockIdx.x + 8 * blockIdx.y;   // vocab slice 0..399
    if (x >= 393) return;
    const int mg = blockIdx.z;                   // 0..1

    const int tid  = threadIdx.x;
    const int lane = tid & 63;
    const int wid  = tid >> 6;
    const int wm   = wid & 1;
    const int wn   = wid >> 1;
    const int quad = lane >> 4;
    const int l15  = lane & 15;
    const int n0   = x * 128;

    bf16x8 bfr[4][4];
#pragma unroll
    for (int nt = 0; nt < 4; ++nt) {
        size_t vg = (size_t)x * 8 + wn * 4 + nt;
#pragma unroll
        for (int kI = 0; kI < 4; ++kI)
            bfr[nt][kI] = *(const bf16x8*)(WvP + ((vg * 4 + kI) * 64 + lane) * 8);
    }

    float bvf[4];
#pragma unroll
    for (int nt = 0; nt < 4; ++nt) {
        int n = n0 + wn * 64 + nt * 16 + l15;
        bvf[nt] = (n < VV) ? bv[n] : -__builtin_huge_valf();
    }

#pragma unroll
    for (int mi = 0; mi < 4; ++mi) {
        const int mi_g = mg * 4 + mi;        // 0..7

        f32x4 acc[4][4];
#pragma unroll
        for (int mt = 0; mt < 4; ++mt)
#pragma unroll
            for (int nt = 0; nt < 4; ++nt) acc[mt][nt] = (f32x4){0.f, 0.f, 0.f, 0.f};

#pragma unroll
        for (int kI = 0; kI < 4; ++kI) {
            bf16x8 afr[4];
#pragma unroll
            for (int mt = 0; mt < 4; ++mt) {
                size_t bg = (size_t)mi_g * 8 + wm * 4 + mt;
                afr[mt] = *(const bf16x8*)(z_pack + ((bg * 4 + kI) * 64 + lane) * 8);
            }
#pragma unroll
            for (int mt = 0; mt < 4; ++mt)
#pragma unroll
                for (int nt = 0; nt < 4; ++nt)
                    acc[mt][nt] = __builtin_amdgcn_mfma_f32_16x16x32_bf16(
                        afr[mt], bfr[nt][kI], acc[mt][nt], 0, 0, 0);
        }

#pragma unroll
        for (int mt = 0; mt < 4; ++mt)
#pragma unroll
            for (int reg = 0; reg < 4; ++reg) {
                float s = 0.f;
#pragma unroll
                for (int nt = 0; nt < 4; ++nt)
                    s += __expf(acc[mt][nt][reg] + bvf[nt]);
                pl[wn][wm * 64 + mt * 16 + quad * 4 + reg][l15] = s;
            }
        __syncthreads();
        if (tid < 128) {
            const float* p0 = &pl[0][tid][0];
            const float* p1 = &pl[1][tid][0];
            float4 a0 = *(const float4*)(p0);
            float4 a1 = *(const float4*)(p0 + 4);
            float4 a2 = *(const float4*)(p0 + 8);
            float4 a3 = *(const float4*)(p0 + 12);
            float4 b0 = *(const float4*)(p1);
            float4 b1 = *(const float4*)(p1 + 4);
            float4 b2 = *(const float4*)(p1 + 8);
            float4 b3 = *(const float4*)(p1 + 12);
            float tot = (a0.x + a0.y + a0.z + a0.w) + (a1.x + a1.y + a1.z + a1.w)
                      + (a2.x + a2.y + a2.z + a2.w) + (a3.x + a3.y + a3.z + a3.w)
                      + (b0.x + b0.y + b0.z + b0.w) + (b1.x + b1.y + b1.z + b1.w)
                      + (b2.x + b2.y + b2.z + b2.w) + (b3.x + b3.y + b3.z + b3.w);
            partial[(size_t)x * 1024 + mi_g * 128 + tid] = tot;
        }
        __syncthreads();
    }
}

// ---------------------------------------------------------------------------
// Kernel 4: reduce partials over 393 vocab slices; final loss.
// ---------------------------------------------------------------------------
__global__ __launch_bounds__(256) void k_reduce(
    const float* __restrict__ partial, const float* __restrict__ ctxsum,
    const float* __restrict__ kl, float* __restrict__ out)
{
    __shared__ float bred[4];
    const int tid = threadIdx.x;
    const int row = blockIdx.x * 16 + (tid >> 4);
    const int part = tid & 15;

    float s = 0.f;
    for (int vb = part; vb < 393; vb += 16)
        s += partial[(size_t)vb * 1024 + row];
    s += __shfl_xor(s, 1, 64);
    s += __shfl_xor(s, 2, 64);
    s += __shfl_xor(s, 4, 64);
    s += __shfl_xor(s, 8, 64);

    float v = 0.f;
    if (part == 0)
        v = ctxsum[row] - 10.f * logf(s) - kl[row];
    v += __shfl_xor(v, 16, 64);
    v += __shfl_xor(v, 32, 64);
    if ((tid & 63) == 0) bred[tid >> 6] = v;
    __syncthreads();
    if (tid == 0)
        atomicAdd(out, (bred[0] + bred[1] + bred[2] + bred[3]) * (1.f / 1024.f));
}

// ---------------------------------------------------------------------------
extern "C" void kernel_launch(void* const* d_in, const int* in_sizes, int n_in,
                              void* d_out, int out_size, void* d_ws, size_t ws_size,
                              hipStream_t stream)
{
    const int*   center_id   = (const int*)d_in[0];
    const int*   context_ids = (const int*)d_in[1];
    const float* epsilon     = (const float*)d_in[2];
    const float* emb         = (const float*)d_in[3];
    const float* prior_means = (const float*)d_in[4];
    const float* prior_vars  = (const float*)d_in[5];
    const float* W_enc       = (const float*)d_in[6];
    const float* b_enc       = (const float*)d_in[7];
    const float* W_mean      = (const float*)d_in[8];
    const float* b_mean      = (const float*)d_in[9];
    const float* W_var       = (const float*)d_in[10];
    const float* b_var       = (const float*)d_in[11];
    const float* W_vocab     = (const float*)d_in[12];
    const float* b_vocab     = (const float*)d_in[13];

    float* out = (float*)d_out;
    char*  ws  = (char*)d_ws;

    size_t off = 0;
    unsigned short* WvP      = (unsigned short*)(ws + off); off += 12877824;  // 50304*128*2
    unsigned short* WeP      = (unsigned short*)(ws + off); off += 131072;    // 256*256*2
    unsigned short* Wmv      = (unsigned short*)(ws + off); off += 131072;    // 256*128*2*2
    unsigned short* z_pack   = (unsigned short*)(ws + off); off += 262144;    // 1024*128*2
    float*          h        = (float*)(ws + off);          off += 1048576;   // 1024*256*4
    float*          kl       = (float*)(ws + off);          off += 4096;
    float*          ctxsum   = (float*)(ws + off);          off += 4096;
    float*          partial  = (float*)(ws + off);          off += 1609728;   // 393*1024*4

    k_prep0<<<16, 256, 0, stream>>>(W_enc, WeP);
    k_main<<<822, 256, 0, stream>>>(center_id, context_ids, emb, WeP, b_enc,
                                    W_vocab, W_mean, W_var, WvP, Wmv, h);
    k_latent<<<256, 512, 0, stream>>>(h, Wmv, b_mean, b_var, epsilon,
                                      center_id, context_ids, WvP, b_vocab,
                                      prior_means, prior_vars, z_pack, kl,
                                      ctxsum, out);
    k_lse<<<dim3(8, 50, 2), 256, 0, stream>>>(z_pack, WvP, b_vocab, partial);
    k_reduce<<<64, 256, 0, stream>>>(partial, ctxsum, kl, out);
}

// Round 5
// 199.540 us; speedup vs baseline: 1.2985x; 1.0179x over previous
//
#include <hip/hip_runtime.h>
#include <math.h>

#define VV 50257
#define VPAD 50304   // 393 * 128
#define DD 128
#define BB 1024
#define CC 10

typedef short bf16x8 __attribute__((ext_vector_type(8)));
typedef float f32x4 __attribute__((ext_vector_type(4)));

__device__ inline float bf2f(unsigned short u) {
    return __uint_as_float(((unsigned)u) << 16);
}
__device__ inline unsigned short f2bf(float f) {
    unsigned u = __float_as_uint(f);
    unsigned r = ((u >> 16) & 1) + 0x7FFF;
    return (unsigned short)((u + r) >> 16);
}

// Fragment-packed operand layout: chunk = (group*NKI + kI)*64 + quad*16 + l15,
// each chunk = 8 bf16 (16B); row group*16+l15, k = kI*32+quad*8+e.

// ---------------------------------------------------------------------------
// Kernel 0 (16 blocks): pack W_enc -> WeP.
// ---------------------------------------------------------------------------
__global__ __launch_bounds__(256) void k_prep0(
    const float* __restrict__ W_enc, unsigned short* __restrict__ WeP)
{
    __shared__ float tl[256][17];
    const int jg = blockIdx.x, tid = threadIdx.x;
#pragma unroll
    for (int i = 0; i < 16; ++i) {
        int idx = i * 256 + tid;
        int k = idx >> 4, j = idx & 15;
        tl[k][j] = W_enc[(size_t)k * 256 + jg * 16 + j];
    }
    __syncthreads();
#pragma unroll
    for (int i = 0; i < 2; ++i) {
        int c = i * 256 + tid;
        int l15 = c & 15, q = (c >> 4) & 3, kI = c >> 6;
        bf16x8 o;
#pragma unroll
        for (int e = 0; e < 8; ++e)
            o[e] = (short)f2bf(tl[kI * 32 + q * 8 + e][l15]);
        *(bf16x8*)(WeP + (((size_t)jg * 8 + kI) * 64 + q * 16 + l15) * 8) = o;
    }
}

// ---------------------------------------------------------------------------
// Kernel 1 (822 blocks):
//   bid 0..31   = fused encoder: h[b][j] = sum_c relu([ce;cx_c] @ W_enc + b).
//                 ce @ W_top computed once (c-invariant); per-c cx staging is
//                 DOUBLE-BUFFERED (LDS rows 32..47) with T14 async split:
//                 issue c+1 global loads BEFORE c's MFMAs, cvt+ds_write after,
//                 one barrier per c -> gather latency hides under compute.
//   bid 32..817 = W_vocab -> WvP fragment pack (HBM stream, overlaps enc).
//   bid 818..821= W_mean/W_var -> Wmv interleave (used only next launch).
// ---------------------------------------------------------------------------
#define AS_STRIDE 520
__global__ __launch_bounds__(256) void k_main(
    const int* __restrict__ center_id, const int* __restrict__ context_ids,
    const float* __restrict__ emb, const unsigned short* __restrict__ WeP,
    const float* __restrict__ b_enc, const float* __restrict__ Wv,
    const float* __restrict__ W_mean, const float* __restrict__ W_var,
    unsigned short* __restrict__ WvP, unsigned short* __restrict__ Wmv,
    float* __restrict__ h)
{
    __shared__ __align__(16) unsigned char smraw[50688];
    const int bid = blockIdx.x, tid = threadIdx.x;

    if (bid >= 818) {
        // ---- Wmv interleave pack ----
        const int b4 = bid - 818;
#pragma unroll
        for (int i = 0; i < 32; ++i) {
            int idx = b4 * 8192 + i * 256 + tid;
            unsigned short m = f2bf(W_mean[idx]);
            unsigned short v = f2bf(W_var[idx]);
            *(ushort2*)(Wmv + (size_t)idx * 2) = make_ushort2(m, v);
        }
        return;
    }

    if (bid >= 32) {
        // ---- W_vocab pack path ----
        float (*tile)[65] = (float (*)[65])smraw;
        const int s = bid - 32;           // 0..785
        const int v0 = s * 64;
#pragma unroll
        for (int i = 0; i < 32; ++i) {
            int idx = tid + i * 256;
            int k = idx >> 6, j = idx & 63;
            int v = v0 + j;
            tile[k][j] = (v < VV) ? Wv[(size_t)k * VV + v] : 0.f;
        }
        __syncthreads();
#pragma unroll
        for (int i = 0; i < 4; ++i) {
            int c = i * 256 + tid;
            int l15 = c & 15, q = (c >> 4) & 3, kI = (c >> 6) & 3, g = c >> 8;
            bf16x8 o;
#pragma unroll
            for (int e = 0; e < 8; ++e)
                o[e] = (short)f2bf(tile[kI * 32 + q * 8 + e][g * 16 + l15]);
            size_t vg = (size_t)s * 4 + g;
            *(bf16x8*)(WvP + ((vg * 4 + kI) * 64 + q * 16 + l15) * 8) = o;
        }
        return;
    }

    // ---- fused encoder path ----
    // As rows: ce = p*8+kI; cx bufA = p*8+4+kI; cx bufB = 32+p*4+kI (48 rows)
    unsigned short* As = (unsigned short*)smraw;                 // 48*520*2 B

    const int lane = tid & 63;
    const int wid  = tid >> 6;
    const int wm   = wid & 1;
    const int wn   = wid >> 1;
    const int quad = lane >> 4;
    const int l15  = lane & 15;

    const int bt = bid & 15;
    const int zt = bid >> 4;
    const int b0 = bt * 64;
    const int n0 = zt * 128;

    const int rlane = tid >> 4;       // 0..15
    const int c8    = tid & 15;       // k-chunk (8 k's)
    const int kIc   = c8 >> 2, qc = c8 & 3;
    const int colB  = (qc * 16 + rlane) * 8;

    // stage ce half (rows p*8 + kIc) once
#pragma unroll
    for (int p = 0; p < 4; ++p) {
        int r = p * 16 + rlane;
        int rid_ce = center_id[b0 + r];
        const float* s0 = emb + (size_t)rid_ce * 128 + c8 * 8;
        float4 a0 = *(const float4*)s0, a1 = *(const float4*)(s0 + 4);
        bf16x8 oa;
        oa[0] = (short)f2bf(a0.x); oa[1] = (short)f2bf(a0.y);
        oa[2] = (short)f2bf(a0.z); oa[3] = (short)f2bf(a0.w);
        oa[4] = (short)f2bf(a1.x); oa[5] = (short)f2bf(a1.y);
        oa[6] = (short)f2bf(a1.z); oa[7] = (short)f2bf(a1.w);
        *(bf16x8*)(As + (size_t)(p * 8 + kIc) * AS_STRIDE + colB) = oa;
    }
    // stage cx for c=0 into buffer A (rows p*8+4+kIc)
#pragma unroll
    for (int p = 0; p < 4; ++p) {
        int r = p * 16 + rlane;
        int rid_cx = context_ids[(b0 + r) * CC + 0];
        const float* s1 = emb + (size_t)rid_cx * 128 + c8 * 8;
        float4 b0v = *(const float4*)s1, b1v = *(const float4*)(s1 + 4);
        bf16x8 ob;
        ob[0] = (short)f2bf(b0v.x); ob[1] = (short)f2bf(b0v.y);
        ob[2] = (short)f2bf(b0v.z); ob[3] = (short)f2bf(b0v.w);
        ob[4] = (short)f2bf(b1v.x); ob[5] = (short)f2bf(b1v.y);
        ob[6] = (short)f2bf(b1v.z); ob[7] = (short)f2bf(b1v.w);
        *(bf16x8*)(As + (size_t)(p * 8 + kIc + 4) * AS_STRIDE + colB) = ob;
    }
    // prefetch cids for c=1 (breaks the dependent-load chain in the loop)
    int cidn[4];
#pragma unroll
    for (int p = 0; p < 4; ++p)
        cidn[p] = context_ids[(b0 + p * 16 + rlane) * CC + 1];
    __syncthreads();

    float benc[4];
#pragma unroll
    for (int nt = 0; nt < 4; ++nt)
        benc[nt] = b_enc[n0 + wn * 64 + nt * 16 + l15];

    // hoist bottom-half B fragments (kI 4..7) into registers
    bf16x8 bbot[4][4];
#pragma unroll
    for (int nt = 0; nt < 4; ++nt) {
        size_t jg = (size_t)zt * 8 + wn * 4 + nt;
#pragma unroll
        for (int kI = 0; kI < 4; ++kI)
            bbot[nt][kI] = *(const bf16x8*)(WeP + ((jg * 8 + kI + 4) * 64 + lane) * 8);
    }

    // acc_ce = ce @ W_top (c-invariant, rows p*8 + kI)
    f32x4 acc_ce[2][4];
#pragma unroll
    for (int mt = 0; mt < 2; ++mt)
#pragma unroll
        for (int nt = 0; nt < 4; ++nt) acc_ce[mt][nt] = (f32x4){0.f, 0.f, 0.f, 0.f};
#pragma unroll
    for (int kI = 0; kI < 4; ++kI) {
        bf16x8 a[2], b[4];
#pragma unroll
        for (int mt = 0; mt < 2; ++mt)
            a[mt] = *(const bf16x8*)(As + (size_t)((wm * 2 + mt) * 8 + kI) * AS_STRIDE + lane * 8);
#pragma unroll
        for (int nt = 0; nt < 4; ++nt) {
            size_t jg = (size_t)zt * 8 + wn * 4 + nt;
            b[nt] = *(const bf16x8*)(WeP + ((jg * 8 + kI) * 64 + lane) * 8);
        }
#pragma unroll
        for (int mt = 0; mt < 2; ++mt)
#pragma unroll
            for (int nt = 0; nt < 4; ++nt)
                acc_ce[mt][nt] = __builtin_amdgcn_mfma_f32_16x16x32_bf16(
                    a[mt], b[nt], acc_ce[mt][nt], 0, 0, 0);
    }

    float hacc[2][4][4];
#pragma unroll
    for (int mt = 0; mt < 2; ++mt)
#pragma unroll
        for (int nt = 0; nt < 4; ++nt)
#pragma unroll
            for (int reg = 0; reg < 4; ++reg) hacc[mt][nt][reg] = 0.f;

    for (int c = 0; c < CC; ++c) {
        // ---- issue next-c gather early (latency hides under MFMA+relu) ----
        float4 ga[4], gb[4];
        if (c < CC - 1) {
#pragma unroll
            for (int p = 0; p < 4; ++p) {
                const float* s1 = emb + (size_t)cidn[p] * 128 + c8 * 8;
                ga[p] = *(const float4*)s1;
                gb[p] = *(const float4*)(s1 + 4);
            }
        }
        int cidn2[4];
        if (c < CC - 2) {
#pragma unroll
            for (int p = 0; p < 4; ++p)
                cidn2[p] = context_ids[(b0 + p * 16 + rlane) * CC + c + 2];
        }

        // ---- compute from buf[c&1] ----
        const int rsel = c & 1;
        f32x4 acc[2][4];
#pragma unroll
        for (int mt = 0; mt < 2; ++mt)
#pragma unroll
            for (int nt = 0; nt < 4; ++nt) acc[mt][nt] = acc_ce[mt][nt];
#pragma unroll
        for (int kI = 0; kI < 4; ++kI) {
            bf16x8 a[2];
#pragma unroll
            for (int mt = 0; mt < 2; ++mt) {
                int pg = wm * 2 + mt;
                int row = rsel ? (32 + pg * 4 + kI) : (pg * 8 + 4 + kI);
                a[mt] = *(const bf16x8*)(As + (size_t)row * AS_STRIDE + lane * 8);
            }
#pragma unroll
            for (int mt = 0; mt < 2; ++mt)
#pragma unroll
                for (int nt = 0; nt < 4; ++nt)
                    acc[mt][nt] = __builtin_amdgcn_mfma_f32_16x16x32_bf16(
                        a[mt], bbot[nt][kI], acc[mt][nt], 0, 0, 0);
        }
#pragma unroll
        for (int mt = 0; mt < 2; ++mt)
#pragma unroll
            for (int nt = 0; nt < 4; ++nt)
#pragma unroll
                for (int reg = 0; reg < 4; ++reg)
                    hacc[mt][nt][reg] += fmaxf(acc[mt][nt][reg] + benc[nt], 0.f);

        // ---- write next-c staging into buf[(c+1)&1] ----
        if (c < CC - 1) {
            const int wsel = (c + 1) & 1;
#pragma unroll
            for (int p = 0; p < 4; ++p) {
                bf16x8 ob;
                ob[0] = (short)f2bf(ga[p].x); ob[1] = (short)f2bf(ga[p].y);
                ob[2] = (short)f2bf(ga[p].z); ob[3] = (short)f2bf(ga[p].w);
                ob[4] = (short)f2bf(gb[p].x); ob[5] = (short)f2bf(gb[p].y);
                ob[6] = (short)f2bf(gb[p].z); ob[7] = (short)f2bf(gb[p].w);
                int row = wsel ? (32 + p * 4 + kIc) : (p * 8 + 4 + kIc);
                *(bf16x8*)(As + (size_t)row * AS_STRIDE + colB) = ob;
            }
#pragma unroll
            for (int p = 0; p < 4; ++p) cidn[p] = cidn2[p];
        }
        __syncthreads();
    }

    // transpose h through LDS for coalesced f32 writes (As dead; reuse smraw)
    float (*Csf)[132] = (float (*)[132])smraw;
#pragma unroll
    for (int mt = 0; mt < 2; ++mt)
#pragma unroll
        for (int nt = 0; nt < 4; ++nt) {
            int col = wn * 64 + nt * 16 + l15;
#pragma unroll
            for (int reg = 0; reg < 4; ++reg) {
                int row = wm * 32 + mt * 16 + quad * 4 + reg;
                Csf[row][col] = hacc[mt][nt][reg];
            }
        }
    __syncthreads();
#pragma unroll
    for (int it = 0; it < 8; ++it) {
        int ch = it * 256 + tid;
        int row = ch >> 5, cg = ch & 31;
        *(float4*)&h[(size_t)(b0 + row) * 256 + n0 + cg * 4] = *(const float4*)&Csf[row][cg * 4];
    }
}

// ---------------------------------------------------------------------------
// Kernel 2: latent heads + KL + context logits. 256 blocks x 512 threads,
// four batch rows per block, split-K 4 over the Wmv GEMV.
// ---------------------------------------------------------------------------
__global__ __launch_bounds__(512) void k_latent(
    const float* __restrict__ h, const unsigned short* __restrict__ Wmv,
    const float* __restrict__ b_mean, const float* __restrict__ b_var,
    const float* __restrict__ epsilon,
    const int* __restrict__ center_id, const int* __restrict__ context_ids,
    const unsigned short* __restrict__ WvP, const float* __restrict__ bv,
    const float* __restrict__ prior_means, const float* __restrict__ prior_vars,
    unsigned short* __restrict__ z_pack, float* __restrict__ kl,
    float* __restrict__ ctxsum, float* __restrict__ out)
{
    __shared__ __align__(16) float hs[4][256];
    __shared__ float mpart[3][4][128], vpart[3][4][128];
    __shared__ float zsh[4][128];
    __shared__ float red[4][2];
    __shared__ float credw[4][2];
    const int tid = threadIdx.x;
    const int b0 = blockIdx.x * 4;

    if (blockIdx.x == 0 && tid == 0) out[0] = 0.f;

    // ---- phase 1: load h ----
    {
        const int col = tid & 255;
        const int rr  = tid >> 8;         // 0,1
#pragma unroll
        for (int r2 = 0; r2 < 2; ++r2) {
            int row = rr * 2 + r2;
            hs[row][col] = h[(size_t)(b0 + row) * 256 + col];
        }
    }
    __syncthreads();

    // ---- phase 2: split-K GEMV for mean/var heads ----
    const int d    = tid & 127;
    const int part = tid >> 7;            // 0..3
    const int kbase = part * 64;
    float m[4], vr[4];
#pragma unroll
    for (int r = 0; r < 4; ++r) {
        m[r]  = part ? 0.f : b_mean[d];
        vr[r] = part ? 0.f : b_var[d];
    }
    for (int k0 = 0; k0 < 64; k0 += 4) {
        float4 h4[4];
#pragma unroll
        for (int r = 0; r < 4; ++r)
            h4[r] = *(const float4*)&hs[r][kbase + k0];
#pragma unroll
        for (int kk = 0; kk < 4; ++kk) {
            ushort2 u = *(const ushort2*)(Wmv + ((size_t)(kbase + k0 + kk) * 128 + d) * 2);
            float wm_ = bf2f(u.x), wv_ = bf2f(u.y);
#pragma unroll
            for (int r = 0; r < 4; ++r) {
                float hk = ((const float*)&h4[r])[kk];
                m[r]  += hk * wm_;
                vr[r] += hk * wv_;
            }
        }
    }
    if (part) {
#pragma unroll
        for (int r = 0; r < 4; ++r) {
            mpart[part - 1][r][d] = m[r];
            vpart[part - 1][r][d] = vr[r];
        }
    }
    __syncthreads();

    // ---- phase 3: combine, var/z/KL (threads 0..127 only) ----
    if (tid < 128) {
        const int wid = tid >> 6;         // 0,1
        const int kIz = d >> 5, qz = (d >> 3) & 3, ez = d & 7;
        const int bg = b0 >> 4;
#pragma unroll
        for (int r = 0; r < 4; ++r) {
            float mm = m[r]  + mpart[0][r][d] + mpart[1][r][d] + mpart[2][r][d];
            float vv = vr[r] + vpart[0][r][d] + vpart[1][r][d] + vpart[2][r][d];

            float var = (vv > 20.f) ? vv : log1pf(__expf(vv));
            float zd = mm + __expf(0.5f * var) * epsilon[d];
            unsigned short zu = f2bf(zd);
            const int bb = b0 + r;
            const int l15b = bb & 15;
            z_pack[(((size_t)(bg * 4 + kIz)) * 64 + qz * 16 + l15b) * 8 + ez] = zu;
            zsh[r][d] = bf2f(zu);

            int cid = center_id[bb];
            float pm  = prior_means[(size_t)cid * 128 + d];
            float pvr = prior_vars[(size_t)cid * 128 + d];
            float pv  = (pvr > 20.f) ? pvr : log1pf(__expf(pvr));
            float diff = pm - mm;
            float t = var / pv + diff * diff / pv - 1.f + logf(pv) - logf(var);
#pragma unroll
            for (int off = 32; off; off >>= 1) t += __shfl_xor(t, off, 64);
            if ((tid & 63) == 0) red[r][wid] = t;
        }
    }
    __syncthreads();

    // ---- phase 4: context logits, wave w = (p-half, row) ----
    {
        const int w     = tid >> 6;       // 0..7
        const int row   = w & 3;
        const int phalf = w >> 2;         // 0: p 0..4, 1: p 5..9
        const int lane  = tid & 63;
        const float z1 = zsh[row][lane];
        const float z2 = zsh[row][lane + 64];
        const int kI1 = lane >> 5, q1 = (lane >> 3) & 3, e1 = lane & 7;
        const int d2  = lane + 64;
        const int kI2 = d2 >> 5,  q2 = (d2 >> 3) & 3,  e2 = d2 & 7;
        float cacc = 0.f;
#pragma unroll
        for (int pp = 0; pp < 5; ++pp) {
            int p = phalf * 5 + pp;
            int cid = context_ids[(b0 + row) * CC + p];
            int vg = cid >> 4, l15v = cid & 15;
            float w1 = bf2f(WvP[(((size_t)(vg * 4 + kI1)) * 64 + q1 * 16 + l15v) * 8 + e1]);
            float w2 = bf2f(WvP[(((size_t)(vg * 4 + kI2)) * 64 + q2 * 16 + l15v) * 8 + e2]);
            float cs = z1 * w1 + z2 * w2;
#pragma unroll
            for (int off = 32; off; off >>= 1) cs += __shfl_xor(cs, off, 64);
            cacc += cs + bv[cid];
        }
        if (lane == 0) credw[row][phalf] = cacc;
    }
    __syncthreads();
    if (tid < 4) {
        kl[b0 + tid]     = 0.5f * (red[tid][0] + red[tid][1]);
        ctxsum[b0 + tid] = credw[tid][0] + credw[tid][1];
    }
}

// ---------------------------------------------------------------------------
// Kernel 3: streaming MFMA GEMM + exp-sum. Grid (8,50,4): x = bx+8*by
// (XCD-pinned slice), mg = bz, 2 mi-steps per block (1600 blocks).
// R4 lesson: the (8,50,2)/800-block variant lost ~2 us to tail quantization
// (800 = 3x256+32 with 2x-fat blocks); finer blocks absorb the tail better
// than the saved B-fragment re-reads are worth. Final reduce stays a SEPARATE
// launch (R3 lesson: in-kernel fence+ticket tail cost ~80 us idle spin).
// ---------------------------------------------------------------------------
__global__ __launch_bounds__(256) void k_lse(
    const unsigned short* __restrict__ z_pack, const unsigned short* __restrict__ WvP,
    const float* __restrict__ bv, float* __restrict__ partial)
{
    __shared__ float pl[2][128][20];
    const int x = blockIdx.x + 8 * blockIdx.y;   // vocab slice 0..399
    if (x >= 393) return;
    const int mg = blockIdx.z;                   // 0..3

    const int tid  = threadIdx.x;
    const int lane = tid & 63;
    const int wid  = tid >> 6;
    const int wm   = wid & 1;
    const int wn   = wid >> 1;
    const int quad = lane >> 4;
    const int l15  = lane & 15;
    const int n0   = x * 128;

    bf16x8 bfr[4][4];
#pragma unroll
    for (int nt = 0; nt < 4; ++nt) {
        size_t vg = (size_t)x * 8 + wn * 4 + nt;
#pragma unroll
        for (int kI = 0; kI < 4; ++kI)
            bfr[nt][kI] = *(const bf16x8*)(WvP + ((vg * 4 + kI) * 64 + lane) * 8);
    }

    float bvf[4];
#pragma unroll
    for (int nt = 0; nt < 4; ++nt) {
        int n = n0 + wn * 64 + nt * 16 + l15;
        bvf[nt] = (n < VV) ? bv[n] : -__builtin_huge_valf();
    }

#pragma unroll
    for (int mi = 0; mi < 2; ++mi) {
        const int mi_g = mg * 2 + mi;        // 0..7

        f32x4 acc[4][4];
#pragma unroll
        for (int mt = 0; mt < 4; ++mt)
#pragma unroll
            for (int nt = 0; nt < 4; ++nt) acc[mt][nt] = (f32x4){0.f, 0.f, 0.f, 0.f};

#pragma unroll
        for (int kI = 0; kI < 4; ++kI) {
            bf16x8 afr[4];
#pragma unroll
            for (int mt = 0; mt < 4; ++mt) {
                size_t bg = (size_t)mi_g * 8 + wm * 4 + mt;
                afr[mt] = *(const bf16x8*)(z_pack + ((bg * 4 + kI) * 64 + lane) * 8);
            }
#pragma unroll
            for (int mt = 0; mt < 4; ++mt)
#pragma unroll
                for (int nt = 0; nt < 4; ++nt)
                    acc[mt][nt] = __builtin_amdgcn_mfma_f32_16x16x32_bf16(
                        afr[mt], bfr[nt][kI], acc[mt][nt], 0, 0, 0);
        }

#pragma unroll
        for (int mt = 0; mt < 4; ++mt)
#pragma unroll
            for (int reg = 0; reg < 4; ++reg) {
                float s = 0.f;
#pragma unroll
                for (int nt = 0; nt < 4; ++nt)
                    s += __expf(acc[mt][nt][reg] + bvf[nt]);
                pl[wn][wm * 64 + mt * 16 + quad * 4 + reg][l15] = s;
            }
        __syncthreads();
        if (tid < 128) {
            const float* p0 = &pl[0][tid][0];
            const float* p1 = &pl[1][tid][0];
            float4 a0 = *(const float4*)(p0);
            float4 a1 = *(const float4*)(p0 + 4);
            float4 a2 = *(const float4*)(p0 + 8);
            float4 a3 = *(const float4*)(p0 + 12);
            float4 b0 = *(const float4*)(p1);
            float4 b1 = *(const float4*)(p1 + 4);
            float4 b2 = *(const float4*)(p1 + 8);
            float4 b3 = *(const float4*)(p1 + 12);
            float tot = (a0.x + a0.y + a0.z + a0.w) + (a1.x + a1.y + a1.z + a1.w)
                      + (a2.x + a2.y + a2.z + a2.w) + (a3.x + a3.y + a3.z + a3.w)
                      + (b0.x + b0.y + b0.z + b0.w) + (b1.x + b1.y + b1.z + b1.w)
                      + (b2.x + b2.y + b2.z + b2.w) + (b3.x + b3.y + b3.z + b3.w);
            partial[(size_t)x * 1024 + mi_g * 128 + tid] = tot;
        }
        __syncthreads();
    }
}

// ---------------------------------------------------------------------------
// Kernel 4: reduce partials over 393 vocab slices; final loss.
// ---------------------------------------------------------------------------
__global__ __launch_bounds__(256) void k_reduce(
    const float* __restrict__ partial, const float* __restrict__ ctxsum,
    const float* __restrict__ kl, float* __restrict__ out)
{
    __shared__ float bred[4];
    const int tid = threadIdx.x;
    const int row = blockIdx.x * 16 + (tid >> 4);
    const int part = tid & 15;

    float s = 0.f;
    for (int vb = part; vb < 393; vb += 16)
        s += partial[(size_t)vb * 1024 + row];
    s += __shfl_xor(s, 1, 64);
    s += __shfl_xor(s, 2, 64);
    s += __shfl_xor(s, 4, 64);
    s += __shfl_xor(s, 8, 64);

    float v = 0.f;
    if (part == 0)
        v = ctxsum[row] - 10.f * logf(s) - kl[row];
    v += __shfl_xor(v, 16, 64);
    v += __shfl_xor(v, 32, 64);
    if ((tid & 63) == 0) bred[tid >> 6] = v;
    __syncthreads();
    if (tid == 0)
        atomicAdd(out, (bred[0] + bred[1] + bred[2] + bred[3]) * (1.f / 1024.f));
}

// ---------------------------------------------------------------------------
extern "C" void kernel_launch(void* const* d_in, const int* in_sizes, int n_in,
                              void* d_out, int out_size, void* d_ws, size_t ws_size,
                              hipStream_t stream)
{
    const int*   center_id   = (const int*)d_in[0];
    const int*   context_ids = (const int*)d_in[1];
    const float* epsilon     = (const float*)d_in[2];
    const float* emb         = (const float*)d_in[3];
    const float* prior_means = (const float*)d_in[4];
    const float* prior_vars  = (const float*)d_in[5];
    const float* W_enc       = (const float*)d_in[6];
    const float* b_enc       = (const float*)d_in[7];
    const float* W_mean      = (const float*)d_in[8];
    const float* b_mean      = (const float*)d_in[9];
    const float* W_var       = (const float*)d_in[10];
    const float* b_var       = (const float*)d_in[11];
    const float* W_vocab     = (const float*)d_in[12];
    const float* b_vocab     = (const float*)d_in[13];

    float* out = (float*)d_out;
    char*  ws  = (char*)d_ws;

    size_t off = 0;
    unsigned short* WvP      = (unsigned short*)(ws + off); off += 12877824;  // 50304*128*2
    unsigned short* WeP      = (unsigned short*)(ws + off); off += 131072;    // 256*256*2
    unsigned short* Wmv      = (unsigned short*)(ws + off); off += 131072;    // 256*128*2*2
    unsigned short* z_pack   = (unsigned short*)(ws + off); off += 262144;    // 1024*128*2
    float*          h        = (float*)(ws + off);          off += 1048576;   // 1024*256*4
    float*          kl       = (float*)(ws + off);          off += 4096;
    float*          ctxsum   = (float*)(ws + off);          off += 4096;
    float*          partial  = (float*)(ws + off);          off += 1609728;   // 393*1024*4

    k_prep0<<<16, 256, 0, stream>>>(W_enc, WeP);
    k_main<<<822, 256, 0, stream>>>(center_id, context_ids, emb, WeP, b_enc,
                                    W_vocab, W_mean, W_var, WvP, Wmv, h);
    k_latent<<<256, 512, 0, stream>>>(h, Wmv, b_mean, b_var, epsilon,
                                      center_id, context_ids, WvP, b_vocab,
                                      prior_means, prior_vars, z_pack, kl,
                                      ctxsum, out);
    k_lse<<<dim3(8, 50, 4), 256, 0, stream>>>(z_pack, WvP, b_vocab, partial);
    k_reduce<<<64, 256, 0, stream>>>(partial, ctxsum, kl, out);
}